// Round 3
// baseline (335.699 us; speedup 1.0000x reference)
//
#include <hip/hip_runtime.h>
#include <hip/hip_bf16.h>

// FeatureExtractionModel on MI355X — round 3.
// k_pack: all MFMA B-fragments (with inline ESM-weight combine)
// k_emb : rec+edge AND pep embedding (unified high-occupancy streamer) -> LN -> bf16
// k_ga  : 4 GraphAttention layers (z-reformulation) + pool MLP (single-wave blocks)
// k_pool2/k_final: double softmax pooling + projection (fp32)

typedef __attribute__((ext_vector_type(8))) short bf16x8;
typedef __attribute__((ext_vector_type(4))) float f32x4;
typedef __attribute__((ext_vector_type(4))) unsigned int u32x4;

#define MFMA(a, b, c) __builtin_amdgcn_mfma_f32_16x16x32_bf16((a), (b), (c), 0, 0, 0)

// WB pack buffer offsets (bf16 elements). Fragment layout per chunk:
//   idx = (chunk*64 + lane)*8 + j
#define WB_REC_OFF   0        // 41 kc x 4 n  (40 ESM-combined + 1 head)
#define WB_PEP_OFF   83968    // 41 kc x 4 n
#define WB_EDGE_OFF  167936   // 1 kc x 4 n
#define WB_P_OFF     169984   // 4 layers x (2 kc x 4 n)   B[o][d]=Wp[d][o]
#define WB_R_OFF     186368   // 4 layers x (2 kc x 8 n)   B[o][k]=Wr[o][k]  (z orientation)
#define WB_V_OFF     219136   // 4 layers x (4 kc x 4 n)   B[k][d]=Wv[d][k]
#define WB_W0_OFF    251904   // 2 kc x 4 n                B[k][o]=W0[o][k]
#define WB_W1_OFF    256000   // 2 kc x 2 n                B[o][o2]=W1[o2][o]
#define WB_W2_OFF    258048   // 1 chunk                   B[j][h]=W2[h][j]
#define WB_TOTAL     258560

__device__ __forceinline__ unsigned short f2bf(float x) {
  __hip_bfloat16 h = __float2bfloat16(x);
  return __builtin_bit_cast(unsigned short, h);
}
__device__ __forceinline__ bf16x8 loadBc(const unsigned short* base, int chunk, int lane) {
  return *(const bf16x8*)(base + ((size_t)chunk * 64 + lane) * 8);
}
__device__ __forceinline__ float tanhf_fast(float x) {
  float e = __expf(2.f * x);
  return 1.f - 2.f / (e + 1.f);
}

// ---------------- pack all B-operand fragments to bf16 (inline ESM combine) ----------------
__global__ __launch_bounds__(256) void k_pack(
    const float* __restrict__ Wresm, const float* __restrict__ Wpesm,
    const float* __restrict__ Wre, const float* __restrict__ Wpe,
    const float* __restrict__ Wedge, const float* __restrict__ Wp,
    const float* __restrict__ Wr, const float* __restrict__ Wv,
    const float* __restrict__ W0, const float* __restrict__ W1,
    const float* __restrict__ W2, unsigned short* __restrict__ WB) {
  const int t = blockIdx.x * 256 + threadIdx.x;
  if (t >= WB_TOTAL) return;
  float v = 0.f;
  if (t < WB_EDGE_OFF) {  // rec / pep: combined ESM + head
    bool isPep = (t >= WB_PEP_OFF);
    int u = isPep ? (t - WB_PEP_OFF) : t;
    int j = u & 7, lane = (u >> 3) & 63, n = (u >> 9) & 3, kc = u >> 11;
    int k = kc * 32 + ((lane >> 4) << 3) + j;
    int col = n * 16 + (lane & 15);
    if (kc < 40) {
      const float* wemb = isPep ? (Wpe + col * 91 + 27) : (Wre + col * 85 + 21);
      const float* wesm = isPep ? Wpesm : Wresm;
      float s = 0.f;
#pragma unroll 8
      for (int e = 0; e < 64; ++e) s += wemb[e] * wesm[e * 1280 + k];
      v = s;
    } else {
      int kl = k - 1280;
      if (isPep) v = (kl < 27) ? Wpe[col * 91 + kl] : 0.f;
      else       v = (kl < 21) ? Wre[col * 85 + kl] : 0.f;
    }
  } else if (t < WB_P_OFF) {  // edge
    int u = t - WB_EDGE_OFF;
    int j = u & 7, lane = (u >> 3) & 63, n = (u >> 9) & 3;
    v = Wedge[(n * 16 + (lane & 15)) * 32 + ((lane >> 4) << 3) + j];
  } else if (t < WB_R_OFF) {  // ga_Wp: B[o][d] = Wp[d][o]
    int u = t - WB_P_OFF;
    int l = u >> 12, w = u & 4095;
    int j = w & 7, lane = (w >> 3) & 63, n = (w >> 9) & 3, kc = w >> 11;
    int o = kc * 32 + ((lane >> 4) << 3) + j;
    int d = n * 16 + (lane & 15);
    v = Wp[l * 4096 + d * 64 + o];
  } else if (t < WB_V_OFF) {  // ga_Wr z-orientation: B[o][k] = Wr[o][k]
    int u = t - WB_R_OFF;
    int l = u >> 13, w = u & 8191;
    int j = w & 7, lane = (w >> 3) & 63, c = (w >> 9) & 15;
    int kc = c >> 3, n = c & 7;
    int o = kc * 32 + ((lane >> 4) << 3) + j;
    int k = n * 16 + (lane & 15);
    v = Wr[l * 8192 + o * 128 + k];
  } else if (t < WB_W0_OFF) {  // ga_Wv: B[k][d] = Wv[d][k]
    int u = t - WB_V_OFF;
    int l = u >> 13, w = u & 8191;
    int j = w & 7, lane = (w >> 3) & 63, n = (w >> 9) & 3, kc = w >> 11;
    int k = kc * 32 + ((lane >> 4) << 3) + j;
    int d = n * 16 + (lane & 15);
    v = Wv[l * 8192 + d * 128 + k];
  } else if (t < WB_W1_OFF) {  // pool_W0
    int u = t - WB_W0_OFF;
    int j = u & 7, lane = (u >> 3) & 63, c = u >> 9;
    int kc = c >> 2, n = c & 3;
    v = W0[(n * 16 + (lane & 15)) * 64 + kc * 32 + ((lane >> 4) << 3) + j];
  } else if (t < WB_W2_OFF) {  // pool_W1
    int u = t - WB_W1_OFF;
    int j = u & 7, lane = (u >> 3) & 63, c = u >> 9;
    int kc = c >> 1, n = c & 1;
    v = W1[(n * 16 + (lane & 15)) * 64 + kc * 32 + ((lane >> 4) << 3) + j];
  } else {  // pool_W2
    int u = t - WB_W2_OFF;
    int j = u & 7, lane = (u >> 3) & 63;
    v = W2[(lane & 15) * 32 + ((lane >> 4) << 3) + j];
  }
  WB[t] = f2bf(v);
}

// ---------------- unified embedding: rec (+edge) tiles and pep tiles ----------------
// grid: [0,1280) rec 64-row tiles; [1280,1408) pep 64-row tiles.
__global__ __launch_bounds__(256) void k_emb(
    const float* __restrict__ rec_feat, const float* __restrict__ edge_feat,
    const float* __restrict__ pep_feat, const unsigned short* __restrict__ WB,
    const float* __restrict__ rec_g, const float* __restrict__ rec_b,
    const float* __restrict__ pep_g, const float* __restrict__ pep_b,
    unsigned short* __restrict__ rec_edge, unsigned short* __restrict__ pep_out) {
  __shared__ float stg[2][2048];  // 2 x [64 rows x 32 cols] f32, 16B-unit XOR swizzle
  const int t = threadIdx.x;
  const int lane = t & 63, w = t >> 6;
  const int quad = lane >> 4, lr = lane & 15;
  const int myrow = w * 16 + lr;
  const int swz = myrow & 7;
  const bool isPep = (blockIdx.x >= 1280);
  const int brow = (isPep ? (int)blockIdx.x - 1280 : (int)blockIdx.x) * 64;
  const float* __restrict__ src = isPep ? pep_feat : rec_feat;
  const int rowlen = isPep ? 1307 : 1322;
  const int head = isPep ? 27 : 42;
  const unsigned short* WBbase = WB + (isPep ? WB_PEP_OFF : WB_REC_OFF);

  const f32x4 fz = {0.f, 0.f, 0.f, 0.f};
  f32x4 acc[4] = {fz, fz, fz, fz};

  float ldr[8];
  auto gload = [&](int kc) {
    const int base = (kc < 40) ? (head + kc * 32) : 0;
    if (!isPep) {  // float2 path: rec rows/cols are 8B-aligned
#pragma unroll
      for (int i = 0; i < 4; ++i) {
        const int f = t + 256 * i;
        const int row = f >> 4, pu = f & 15;
        const float2 v = *(const float2*)(src + (size_t)(brow + row) * rowlen + base + pu * 2);
        ldr[2 * i] = v.x; ldr[2 * i + 1] = v.y;
      }
    } else {  // pep rows are only 4B-aligned -> scalar
#pragma unroll
      for (int i = 0; i < 8; ++i) {
        const int f = t + 256 * i;
        const int row = f >> 5, col = f & 31;
        ldr[i] = src[(size_t)(brow + row) * rowlen + base + col];
      }
    }
  };
  auto swrite = [&](int b) {
    if (!isPep) {
#pragma unroll
      for (int i = 0; i < 4; ++i) {
        const int f = t + 256 * i;
        const int row = f >> 4, pu = f & 15;
        const int u = pu >> 1, h = pu & 1;
        float2 v; v.x = ldr[2 * i]; v.y = ldr[2 * i + 1];
        *(float2*)(&stg[b][row * 32 + ((u ^ (row & 7)) << 2) + (h << 1)]) = v;
      }
    } else {
#pragma unroll
      for (int i = 0; i < 8; ++i) {
        const int f = t + 256 * i;
        const int row = f >> 5, col = f & 31;
        stg[b][row * 32 + (((col >> 2) ^ (row & 7)) << 2) + (col & 3)] = ldr[i];
      }
    }
  };

  gload(0); swrite(0);
  __syncthreads();
  for (int kc = 0; kc < 41; ++kc) {
    if (kc < 40) gload(kc + 1);
    const float4 r0 = *(const float4*)(&stg[kc & 1][myrow * 32 + ((((quad << 1) | 0) ^ swz) << 2)]);
    const float4 r1 = *(const float4*)(&stg[kc & 1][myrow * 32 + ((((quad << 1) | 1) ^ swz) << 2)]);
    bf16x8 a;
#pragma unroll
    for (int j = 0; j < 4; ++j) { a[j] = (short)f2bf(r0[j]); a[4 + j] = (short)f2bf(r1[j]); }
    const unsigned short* wb = WBbase + kc * 2048;
#pragma unroll
    for (int n = 0; n < 4; ++n) acc[n] = MFMA(a, loadBc(wb, n, lane), acc[n]);
    if (kc < 40) swrite((kc + 1) & 1);
    __syncthreads();
  }

  // LN stats
  float s[4], sq[4];
#pragma unroll
  for (int i = 0; i < 4; ++i) {
    s[i] = acc[0][i] + acc[1][i] + acc[2][i] + acc[3][i];
    sq[i] = acc[0][i] * acc[0][i] + acc[1][i] * acc[1][i] +
            acc[2][i] * acc[2][i] + acc[3][i] * acc[3][i];
  }
#pragma unroll
  for (int msk = 1; msk < 16; msk <<= 1) {
#pragma unroll
    for (int i = 0; i < 4; ++i) {
      s[i] += __shfl_xor(s[i], msk);
      sq[i] += __shfl_xor(sq[i], msk);
    }
  }
  const float* gp = isPep ? pep_g : rec_g;
  const float* bp = isPep ? pep_b : rec_b;
  float gv[4], bvl[4];
#pragma unroll
  for (int n = 0; n < 4; ++n) { gv[n] = gp[lr + 16 * n]; bvl[n] = bp[lr + 16 * n]; }

  if (!isPep) {
    f32x4 acce[4] = {fz, fz, fz, fz};
    {  // edge embedding (aligned direct loads)
      const float* p = edge_feat + (size_t)(brow + myrow) * 32 + quad * 8;
      const float4 f0 = *(const float4*)(p);
      const float4 f1 = *(const float4*)(p + 4);
      bf16x8 a;
#pragma unroll
      for (int j = 0; j < 4; ++j) { a[j] = (short)f2bf(f0[j]); a[4 + j] = (short)f2bf(f1[j]); }
#pragma unroll
      for (int n = 0; n < 4; ++n) acce[n] = MFMA(a, loadBc(WB + WB_EDGE_OFF, n, lane), acce[n]);
    }
#pragma unroll
    for (int i = 0; i < 4; ++i) {
      const float mean = s[i] * (1.f / 64.f);
      const float var = sq[i] * (1.f / 64.f) - mean * mean;
      const float rstd = rsqrtf(var + 1e-5f);
      const int row = brow + w * 16 + quad * 4 + i;
      unsigned short* dst = rec_edge + (size_t)row * 128;
#pragma unroll
      for (int n = 0; n < 4; ++n) {
        dst[lr + 16 * n] = f2bf((acc[n][i] - mean) * rstd * gv[n] + bvl[n]);
        dst[64 + lr + 16 * n] = f2bf(acce[n][i]);
      }
    }
  } else {
#pragma unroll
    for (int i = 0; i < 4; ++i) {
      const float mean = s[i] * (1.f / 64.f);
      const float var = sq[i] * (1.f / 64.f) - mean * mean;
      const float rstd = rsqrtf(var + 1e-5f);
      const int row = brow + w * 16 + quad * 4 + i;
      unsigned short* dst = pep_out + (size_t)row * 64;
#pragma unroll
      for (int n = 0; n < 4; ++n)
        dst[lr + 16 * n] = f2bf((acc[n][i] - mean) * rstd * gv[n] + bvl[n]);
    }
  }
}

// ---------------- 4 GA layers + pool MLP (16 positions per single-wave block) ----------------
__global__ __launch_bounds__(64) void k_ga(
    const unsigned short* __restrict__ rec_edge, const unsigned short* __restrict__ pep_bf,
    const unsigned short* __restrict__ WB,
    const float* __restrict__ ga_bp, const float* __restrict__ ga_bv,
    const float* __restrict__ pool_g, const float* __restrict__ pool_b,
    float* __restrict__ dbuf, float* __restrict__ logitsT) {
  __shared__ unsigned short re_s[20480];  // [16 p][10 r][128] bf16, 16B units XOR-swz by p&7
  __shared__ float z_s[16 * 132];         // z transpose (also reused for dbuf transpose)
  __shared__ unsigned short pep_s[1024];  // [16][64] bf16, swizzled
  __shared__ unsigned short q_s[1024];    // [16][64] bf16, swizzled (q / d / h0 / h1)
  __shared__ float bias_s[512];           // bp[4][64], bv[4][64]

  const int t = threadIdx.x;
  const int quad = t >> 4, lr = t & 15;
  const int swz = lr & 7;
  const int pbase = blockIdx.x * 16;
  const f32x4 fz = {0.f, 0.f, 0.f, 0.f};

  // ---- bias + pep frags + rec_edge staging ----
#pragma unroll
  for (int i = 0; i < 4; ++i) {
    int f = t + 64 * i;
    bias_s[f] = ga_bp[f];
    bias_s[256 + f] = ga_bv[f];
  }
#pragma unroll
  for (int i = 0; i < 2; ++i) {
    const int G = t + 64 * i;
    const int p = G >> 3, gg = G & 7;
    const bf16x8 v = *(const bf16x8*)(pep_bf + (size_t)(pbase + p) * 64 + gg * 8);
    *(bf16x8*)(pep_s + p * 64 + ((gg ^ (p & 7)) << 3)) = v;
  }
  {
    const uint4* src = (const uint4*)(rec_edge + (size_t)pbase * 1280);
    for (int i = 0; i < 40; ++i) {
      int g = t + 64 * i;
      uint4 v = src[g];
      int p = g / 160, rem = g - p * 160;
      int r = rem >> 4, u = rem & 15;
      *(uint4*)(re_s + p * 1280 + r * 128 + ((u ^ (p & 7)) << 3)) = v;
    }
  }

  auto bwrite = [&](unsigned short* buf, int p, int col, unsigned short val) {
    buf[p * 64 + ((((col >> 3)) ^ (p & 7)) << 3) + (col & 7)] = val;
  };
  auto bfrag = [&](const unsigned short* buf, int kc) -> bf16x8 {
    return *(const bf16x8*)(buf + lr * 64 + ((((kc << 2) + quad) ^ swz) << 3));
  };

  // ---- 4 GraphAttention layers ----
  f32x4 pcur[4];
  for (int l = 0; l < 4; ++l) {
    const unsigned short* WBp = WB + WB_P_OFF + l * 4096;
    const unsigned short* WBr = WB + WB_R_OFF + l * 8192;
    const unsigned short* WBv = WB + WB_V_OFF + l * 8192;
    // q = pep @ Wp^T + bp
    f32x4 qa[4] = {fz, fz, fz, fz};
#pragma unroll
    for (int kc = 0; kc < 2; ++kc) {
      bf16x8 a = bfrag(pep_s, kc);
#pragma unroll
      for (int n = 0; n < 4; ++n) qa[n] = MFMA(a, loadBc(WBp, kc * 4 + n, t), qa[n]);
    }
#pragma unroll
    for (int n = 0; n < 4; ++n) {
      const float bpv = bias_s[l * 64 + lr + 16 * n];
#pragma unroll
      for (int i = 0; i < 4; ++i) qa[n][i] += bpv;
    }
    // q -> bf16 frags
#pragma unroll
    for (int n = 0; n < 4; ++n)
#pragma unroll
      for (int i = 0; i < 4; ++i)
        bwrite(q_s, quad * 4 + i, lr + 16 * n, f2bf(qa[n][i]));
    const bf16x8 aq0 = bfrag(q_s, 0), aq1 = bfrag(q_s, 1);
    // z = Wr^T q   [16 p x 128 k]
    f32x4 za[8] = {fz, fz, fz, fz, fz, fz, fz, fz};
#pragma unroll
    for (int n = 0; n < 8; ++n) za[n] = MFMA(aq0, loadBc(WBr, n, t), za[n]);
#pragma unroll
    for (int n = 0; n < 8; ++n) za[n] = MFMA(aq1, loadBc(WBr, 8 + n, t), za[n]);
    // transpose z via LDS -> per-lane A-layout (fp32)
#pragma unroll
    for (int n = 0; n < 8; ++n)
#pragma unroll
      for (int i = 0; i < 4; ++i)
        z_s[(quad * 4 + i) * 132 + lr + 16 * n] = za[n][i];
    float4 zr[8];
#pragma unroll
    for (int c = 0; c < 8; ++c)
      zr[c] = *(const float4*)(&z_s[lr * 132 + quad * 8 + (c >> 1) * 32 + (c & 1) * 4]);
    // logits: lg[r] = (z[p] . re[p][r]) / 8   (q.br is softmax-invariant, dropped)
    float lg[10];
#pragma unroll 2
    for (int r = 0; r < 10; ++r) {
      float part = 0.f;
#pragma unroll
      for (int kc = 0; kc < 4; ++kc) {
        bf16x8 rf = *(const bf16x8*)(re_s + lr * 1280 + r * 128 + (((quad + 4 * kc) ^ swz) << 3));
        u32x4 wv = __builtin_bit_cast(u32x4, rf);
#pragma unroll
        for (int m = 0; m < 4; ++m) {
          const float lo = __builtin_bit_cast(float, wv[m] << 16);
          const float hi = __builtin_bit_cast(float, wv[m] & 0xffff0000u);
          part += lo * zr[kc * 2 + (m >> 1)][(m & 1) * 2 + 0];
          part += hi * zr[kc * 2 + (m >> 1)][(m & 1) * 2 + 1];
        }
      }
      part += __shfl_xor(part, 16);
      part += __shfl_xor(part, 32);
      lg[r] = part * 0.125f;
    }
    // softmax over r (per-lane, replicated)
    float mx = lg[0];
#pragma unroll
    for (int r = 1; r < 10; ++r) mx = fmaxf(mx, lg[r]);
    float ssum = 0.f;
#pragma unroll
    for (int r = 0; r < 10; ++r) { lg[r] = __expf(lg[r] - mx); ssum += lg[r]; }
    const float inv = 1.f / ssum;
#pragma unroll
    for (int r = 0; r < 10; ++r) lg[r] *= inv;
    // ws = sum_r a[r] * re[p][r]   (A-layout per lane)
    float ws[4][8] = {};
#pragma unroll 2
    for (int r = 0; r < 10; ++r) {
#pragma unroll
      for (int kc = 0; kc < 4; ++kc) {
        bf16x8 rf = *(const bf16x8*)(re_s + lr * 1280 + r * 128 + (((quad + 4 * kc) ^ swz) << 3));
        u32x4 wv = __builtin_bit_cast(u32x4, rf);
#pragma unroll
        for (int m = 0; m < 4; ++m) {
          const float lo = __builtin_bit_cast(float, wv[m] << 16);
          const float hi = __builtin_bit_cast(float, wv[m] & 0xffff0000u);
          ws[kc][2 * m] += lg[r] * lo;
          ws[kc][2 * m + 1] += lg[r] * hi;
        }
      }
    }
    bf16x8 wf[4];
#pragma unroll
    for (int kc = 0; kc < 4; ++kc)
#pragma unroll
      for (int j = 0; j < 8; ++j) wf[kc][j] = (short)f2bf(ws[kc][j]);
    // out = ws @ Wv^T ; pep_new = q + out + bv  (sum a = 1)
    f32x4 oa[4] = {fz, fz, fz, fz};
#pragma unroll
    for (int kc = 0; kc < 4; ++kc)
#pragma unroll
      for (int n = 0; n < 4; ++n) oa[n] = MFMA(wf[kc], loadBc(WBv, kc * 4 + n, t), oa[n]);
#pragma unroll
    for (int n = 0; n < 4; ++n) {
      const float bvv = bias_s[256 + l * 64 + lr + 16 * n];
#pragma unroll
      for (int i = 0; i < 4; ++i) pcur[n][i] = qa[n][i] + oa[n][i] + bvv;
    }
#pragma unroll
    for (int n = 0; n < 4; ++n)
#pragma unroll
      for (int i = 0; i < 4; ++i)
        bwrite(pep_s, quad * 4 + i, lr + 16 * n, f2bf(pcur[n][i]));
  }

  // ---- pooling head: d = LN(pep); dbuf; logits = W2 tanh(W1 tanh(W0 d)) ----
  {
    float s[4], sq[4];
#pragma unroll
    for (int i = 0; i < 4; ++i) {
      s[i] = pcur[0][i] + pcur[1][i] + pcur[2][i] + pcur[3][i];
      sq[i] = pcur[0][i] * pcur[0][i] + pcur[1][i] * pcur[1][i] +
              pcur[2][i] * pcur[2][i] + pcur[3][i] * pcur[3][i];
    }
#pragma unroll
    for (int msk = 1; msk < 16; msk <<= 1) {
#pragma unroll
      for (int i = 0; i < 4; ++i) {
        s[i] += __shfl_xor(s[i], msk);
        sq[i] += __shfl_xor(sq[i], msk);
      }
    }
    float gv[4], bv2[4];
#pragma unroll
    for (int n = 0; n < 4; ++n) { gv[n] = pool_g[lr + 16 * n]; bv2[n] = pool_b[lr + 16 * n]; }
    f32x4 d[4];
#pragma unroll
    for (int i = 0; i < 4; ++i) {
      const float mean = s[i] * (1.f / 64.f);
      const float var = sq[i] * (1.f / 64.f) - mean * mean;
      const float rstd = rsqrtf(var + 1e-5f);
#pragma unroll
      for (int n = 0; n < 4; ++n) d[n][i] = (pcur[n][i] - mean) * rstd * gv[n] + bv2[n];
    }
    // dbuf (fp32) via LDS transpose -> coalesced store (reuse z_s as float scratch)
#pragma unroll
    for (int n = 0; n < 4; ++n)
#pragma unroll
      for (int i = 0; i < 4; ++i)
        z_s[(quad * 4 + i) * 64 + lr + 16 * n] = d[n][i];
#pragma unroll
    for (int i = 0; i < 4; ++i) {
      const float4 v = *(const float4*)(&z_s[i * 256 + t * 4]);
      *(float4*)(dbuf + (size_t)pbase * 64 + i * 256 + t * 4) = v;
    }
    // d -> bf16 frags
#pragma unroll
    for (int n = 0; n < 4; ++n)
#pragma unroll
      for (int i = 0; i < 4; ++i)
        bwrite(q_s, quad * 4 + i, lr + 16 * n, f2bf(d[n][i]));
    const bf16x8 ad0 = bfrag(q_s, 0), ad1 = bfrag(q_s, 1);
    f32x4 h0[4] = {fz, fz, fz, fz};
#pragma unroll
    for (int n = 0; n < 4; ++n) {
      h0[n] = MFMA(ad0, loadBc(WB + WB_W0_OFF, n, t), h0[n]);
      h0[n] = MFMA(ad1, loadBc(WB + WB_W0_OFF, 4 + n, t), h0[n]);
    }
#pragma unroll
    for (int n = 0; n < 4; ++n)
#pragma unroll
      for (int i = 0; i < 4; ++i)
        bwrite(q_s, quad * 4 + i, lr + 16 * n, f2bf(tanhf_fast(h0[n][i])));
    const bf16x8 ah00 = bfrag(q_s, 0), ah01 = bfrag(q_s, 1);
    f32x4 h1[2] = {fz, fz};
#pragma unroll
    for (int n = 0; n < 2; ++n) {
      h1[n] = MFMA(ah00, loadBc(WB + WB_W1_OFF, n, t), h1[n]);
      h1[n] = MFMA(ah01, loadBc(WB + WB_W1_OFF, 2 + n, t), h1[n]);
    }
#pragma unroll
    for (int n = 0; n < 2; ++n)
#pragma unroll
      for (int i = 0; i < 4; ++i)
        bwrite(q_s, quad * 4 + i, lr + 16 * n, f2bf(tanhf_fast(h1[n][i])));
    const bf16x8 ah1 = bfrag(q_s, 0);
    f32x4 lac = MFMA(ah1, loadBc(WB + WB_W2_OFF, 0, t), fz);
    const int b = pbase >> 11, sx0 = pbase & 2047;
#pragma unroll
    for (int i = 0; i < 4; ++i)
      logitsT[(size_t)(b * 16 + lr) * 2048 + sx0 + quad * 4 + i] = lac[i];
  }
}

// ---------------- double softmax over s + attended ----------------
__global__ __launch_bounds__(256) void k_pool2(
    const float* __restrict__ logitsT, const float* __restrict__ dbuf,
    float* __restrict__ attended) {
  __shared__ float sh[2048];
  __shared__ float red[8];
  __shared__ float accs[4][64];
  const int bh = blockIdx.x, b = bh >> 4;
  const int tid = threadIdx.x, lane = tid & 63, wid = tid >> 6;
  const float* lrow = logitsT + (size_t)bh * 2048;

  float m = -1e30f;
  for (int sx = tid; sx < 2048; sx += 256) {
    float v = lrow[sx];
    sh[sx] = v;
    m = fmaxf(m, v);
  }
#pragma unroll
  for (int msk = 1; msk < 64; msk <<= 1) m = fmaxf(m, __shfl_xor(m, msk));
  if (lane == 0) red[wid] = m;
  __syncthreads();
  m = fmaxf(fmaxf(red[0], red[1]), fmaxf(red[2], red[3]));

  float s1 = 0.f;
  for (int sx = tid; sx < 2048; sx += 256) {
    float e = __expf(sh[sx] - m);
    sh[sx] = e;
    s1 += e;
  }
#pragma unroll
  for (int msk = 1; msk < 64; msk <<= 1) s1 += __shfl_xor(s1, msk);
  __syncthreads();
  if (lane == 0) red[4 + wid] = s1;
  __syncthreads();
  s1 = red[4] + red[5] + red[6] + red[7];
  const float invS1 = 1.f / s1;

  float s2 = 0.f;
  for (int sx = tid; sx < 2048; sx += 256) {
    float e2 = __expf((sh[sx] - 1.f) * invS1);
    sh[sx] = e2;
    s2 += e2;
  }
#pragma unroll
  for (int msk = 1; msk < 64; msk <<= 1) s2 += __shfl_xor(s2, msk);
  __syncthreads();
  if (lane == 0) red[wid] = s2;
  __syncthreads();
  s2 = red[0] + red[1] + red[2] + red[3];
  const float invS2 = 1.f / s2;

  float acc = 0.f;
  for (int sx = wid; sx < 2048; sx += 4)
    acc += sh[sx] * dbuf[((size_t)b * 2048 + sx) * 64 + lane];
  accs[wid][lane] = acc * invS2;
  __syncthreads();
  if (tid < 64)
    attended[(size_t)bh * 64 + tid] =
        accs[0][tid] + accs[1][tid] + accs[2][tid] + accs[3][tid];
}

// ---------------- pooled mean over heads + final projection ----------------
__global__ __launch_bounds__(256) void k_final(
    const float* __restrict__ attended, const float* __restrict__ W,
    const float* __restrict__ bias, float* __restrict__ out) {
  __shared__ float pooled[4][64];
  const int tid = threadIdx.x;
  {
    const int b = tid >> 6, d = tid & 63;
    float s = 0.f;
#pragma unroll
    for (int h = 0; h < 16; ++h) s += attended[((size_t)b * 16 + h) * 64 + d];
    pooled[b][d] = s * (1.f / 16.f);
  }
  __syncthreads();
  if (tid < 128) {
    const int b = tid >> 5, j = tid & 31;
    float s = bias[j];
#pragma unroll
    for (int d2 = 0; d2 < 64; ++d2) s += pooled[b][d2] * W[j * 64 + d2];
    out[b * 32 + j] = s;
  }
}

extern "C" void kernel_launch(void* const* d_in, const int* in_sizes, int n_in,
                              void* d_out, int out_size, void* d_ws, size_t ws_size,
                              hipStream_t stream) {
  const float* pep_feat = (const float*)d_in[0];
  const float* rec_feat = (const float*)d_in[1];
  const float* edge_feat = (const float*)d_in[2];
  const float* W_rec_esm = (const float*)d_in[3];
  const float* W_pep_esm = (const float*)d_in[4];
  const float* W_pep_emb = (const float*)d_in[5];
  const float* W_rec_emb = (const float*)d_in[6];
  const float* W_edge_emb = (const float*)d_in[7];
  const float* pep_ln_g = (const float*)d_in[8];
  const float* pep_ln_b = (const float*)d_in[9];
  const float* rec_ln_g = (const float*)d_in[10];
  const float* rec_ln_b = (const float*)d_in[11];
  const float* ga_Wp = (const float*)d_in[12];
  const float* ga_bp = (const float*)d_in[13];
  const float* ga_Wr = (const float*)d_in[14];
  const float* ga_br = (const float*)d_in[15];
  const float* ga_Wv = (const float*)d_in[16];
  const float* ga_bv = (const float*)d_in[17];
  const float* pool_ln_g = (const float*)d_in[18];
  const float* pool_ln_b = (const float*)d_in[19];
  const float* pool_W0 = (const float*)d_in[20];
  const float* pool_W1 = (const float*)d_in[21];
  const float* pool_W2 = (const float*)d_in[22];
  const float* mlp_W = (const float*)d_in[23];
  const float* mlp_b = (const float*)d_in[24];
  float* out = (float*)d_out;
  (void)ga_br;  // softmax-invariant, algebraically dropped
  (void)ws_size; (void)in_sizes; (void)n_in; (void)out_size;

  char* ws = (char*)d_ws;
  unsigned short* WB = (unsigned short*)(ws);                 // 517120 B (pad->524288)
  unsigned short* rec_edge = (unsigned short*)(ws + 524288);  // 20971520 B
  unsigned short* pep_bf = (unsigned short*)(ws + 21495808);  // 1048576 B
  float* dbuf = (float*)(ws + 22544384);                      // 2097152 B
  float* logitsT = (float*)(ws + 24641536);                   // 524288 B
  float* attended = (float*)(ws + 25165824);                  // 16384 B

  k_pack<<<1010, 256, 0, stream>>>(W_rec_esm, W_pep_esm, W_rec_emb, W_pep_emb,
                                   W_edge_emb, ga_Wp, ga_Wr, ga_Wv,
                                   pool_W0, pool_W1, pool_W2, WB);
  k_emb<<<1408, 256, 0, stream>>>(rec_feat, edge_feat, pep_feat, WB,
                                  rec_ln_g, rec_ln_b, pep_ln_g, pep_ln_b,
                                  rec_edge, pep_bf);
  k_ga<<<512, 64, 0, stream>>>(rec_edge, pep_bf, WB, ga_bp, ga_bv,
                               pool_ln_g, pool_ln_b, dbuf, logitsT);
  k_pool2<<<64, 256, 0, stream>>>(logitsT, dbuf, attended);
  k_final<<<1, 256, 0, stream>>>(attended, mlp_W, mlp_b, out);
}